// Round 10
// baseline (427.901 us; speedup 1.0000x reference)
//
#include <hip/hip_runtime.h>
#include <hip/hip_bf16.h>
#include <cstdint>
#include <cstddef>

typedef unsigned short u16;
typedef __attribute__((ext_vector_type(4))) unsigned short u16x4;
typedef __attribute__((ext_vector_type(8))) unsigned short u16x8;
typedef __attribute__((ext_vector_type(8))) short bf16x8;
typedef __attribute__((ext_vector_type(4))) float f32x4;

#define BB 8
#define NN 4096
#define CC 768
#define HH 12
#define DD 64
#define NHEADS 96           // B*H
#define QKVSZ 25165824LL    // 96*4096*64 elements per q/k/v plane

__device__ inline float b2f(u16 u) { return __uint_as_float(((unsigned)u) << 16); }
__device__ inline u16 f2b(float f) {
    unsigned u = __float_as_uint(f);
    return (u16)((u + 0x7fffu + ((u >> 16) & 1u)) >> 16);
}
__device__ inline f32x4 zero4() { f32x4 z = {0.f, 0.f, 0.f, 0.f}; return z; }

// direct global->LDS DMA, 16B per lane. LDS dest is wave-uniform base
// (HW adds lane*16); global src is per-lane (pre-swizzled for conflict-free reads).
__device__ __forceinline__ void gl_lds16(const u16* g, u16* l) {
    __builtin_amdgcn_global_load_lds(
        (const __attribute__((address_space(1))) void*)g,
        (__attribute__((address_space(3))) void*)l, 16, 0, 0);
}

// ---------------------------------------------------------------- fused casts f32->bf16 (x, qkv_w, proj_w)
__global__ void cast_all(const float* __restrict__ x, const float* __restrict__ w1,
                         const float* __restrict__ w2, u16* __restrict__ xb,
                         u16* __restrict__ wqkv, u16* __restrict__ wproj) {
    const long n0 = 25165824, n1 = 1769472, n2 = 589824;
    long i0 = (long)(blockIdx.x * blockDim.x + threadIdx.x) * 4;
    long stride = (long)gridDim.x * blockDim.x * 4;
    for (long j = i0; j < n0 + n1 + n2; j += stride) {
        const float* s; u16* d; long k;
        if (j < n0)            { s = x;  d = xb;    k = j; }
        else if (j < n0 + n1)  { s = w1; d = wqkv;  k = j - n0; }
        else                   { s = w2; d = wproj; k = j - n0 - n1; }
        float4 v = *(const float4*)(s + k);
        u16x4 o;
        o[0] = f2b(v.x); o[1] = f2b(v.y); o[2] = f2b(v.z); o[3] = f2b(v.w);
        *(u16x4*)(d + k) = o;
    }
}

// ---------------------------------------------------------------- 256x256 bf16 GEMM, 8-phase counted-vmcnt schedule
// Y[r,c] = sum_j A[r,j]*Bm[c,j].  K=768 (12 K-tiles of 64, 6 iters x 2 tiles).
// 512 thr = 8 waves (wr=wid>>2 in {0,1}, wc=wid&3 in {0..3}).
// HALF-PHASED quad mapping (the r9 bug-fix): quad(mh,nh) reads ONLY A-half mh
// and B-half nh:  A-row = mh*128 + wr*64 + ii*16 + li   (ii 0..3)
//                 B-col = nh*128 + wc*32 + jj*16 + li   (jj 0..1)
// so each wave's span stays inside the half -> staged halves never race with
// live reads.  Quads per tile in order (0,0),(0,1),(1,1),(1,0).
// Stage slots (iter I, te=2I buf0, to=te+1 buf1), one half-stage (2 gl_lds16) per phase:
//   p0:A-h1(to) p1:B-h0(to) p2:A-h0(te+2) p3:B-h1(te+2)
//   p4:A-h1(te+2) p5:B-h0(te+2) p6:A-h0(to+2) p7:B-h1(to+2)
// each half's writer issues strictly after its last reader's phase barrier
// (liveness: bufX A-h0 dead after its 2nd quad, etc. — full table re-derived).
// vmcnt(4) at p0/p4 = exactly the 2 youngest half-stages in flight; last-iter
// p4 drains to 0.  Swizzle identical to the validated round-5/7 involution.
// MODE 0: scatter-store qkv bf16 [3][B][H][N][64].  MODE 1: +bias, fp32 [M][768].
template <int MODE>
__global__ __launch_bounds__(512, 2) void gemm256p(const u16* __restrict__ A, const u16* __restrict__ Bm,
                                                   const float* __restrict__ bias, void* __restrict__ out,
                                                   int ncol) {
    constexpr int K = 768;
    constexpr int NT = K / 64;        // 12
    constexpr int NI = NT / 2;        // 6
    __shared__ __align__(16) u16 lA[2][256 * 64];
    __shared__ __align__(16) u16 lB[2][256 * 64];
    const int tid = threadIdx.x;
    const int lane = tid & 63, wid = tid >> 6;
    const int wr = wid >> 2, wc = wid & 3;
    const int li = lane & 15, g = lane >> 4;

    const int nwg = gridDim.x, chunk = nwg >> 3;
    const int swz = ((int)blockIdx.x & 7) * chunk + ((int)blockIdx.x >> 3);
    const int col0 = (swz % ncol) * 256;
    const int row0 = (swz / ncol) * 256;

    const int lrow = lane >> 3;                     // row within 8-row group
    const int lcolsw = ((lane & 7) ^ lrow) * 8;     // inverse-swizzled col (elements)

    f32x4 acc[8][4];
#pragma unroll
    for (int i = 0; i < 8; ++i)
#pragma unroll
        for (int j = 0; j < 4; ++j) acc[i][j] = zero4();

    // stage half h (0/1) of K-tile tau: 2 gl_lds16 per wave (16 rows)
    auto stA = [&](int h, int tau) {
        const int rb = h * 128 + wid * 16;
        u16* dst = &lA[tau & 1][rb * 64];
        const u16* src = A + (size_t)(row0 + rb + lrow) * K + tau * 64 + lcolsw;
        gl_lds16(src, dst);
        gl_lds16(src + (size_t)8 * K, dst + 8 * 64);
    };
    auto stB = [&](int h, int tau) {
        const int rb = h * 128 + wid * 16;
        u16* dst = &lB[tau & 1][rb * 64];
        const u16* src = Bm + (size_t)(col0 + rb + lrow) * K + tau * 64 + lcolsw;
        gl_lds16(src, dst);
        gl_lds16(src + (size_t)8 * K, dst + 8 * 64);
    };
    // compute quadrant (mh, nh) of tile tau: 16 MFMA, reads only A-half mh / B-half nh
    auto quad = [&](int tau, int mh, int nh) {
        const char* baseA = (const char*)&lA[tau & 1][0];
        const char* baseB = (const char*)&lB[tau & 1][0];
        bf16x8 bfr[2][2];
#pragma unroll
        for (int jj = 0; jj < 2; ++jj) {
            int rb = nh * 128 + wc * 32 + jj * 16 + li;
#pragma unroll
            for (int k2 = 0; k2 < 2; ++k2)
                bfr[jj][k2] = *(const bf16x8*)(baseB + ((rb * 128 + k2 * 64 + g * 16) ^ ((rb & 7) << 4)));
        }
        __builtin_amdgcn_s_setprio(1);
#pragma unroll
        for (int ii = 0; ii < 4; ++ii) {
            int ra = mh * 128 + wr * 64 + ii * 16 + li;
            bf16x8 af0 = *(const bf16x8*)(baseA + ((ra * 128 + g * 16) ^ ((ra & 7) << 4)));
            bf16x8 af1 = *(const bf16x8*)(baseA + ((ra * 128 + 64 + g * 16) ^ ((ra & 7) << 4)));
#pragma unroll
            for (int jj = 0; jj < 2; ++jj) {
                acc[mh * 4 + ii][nh * 2 + jj] =
                    __builtin_amdgcn_mfma_f32_16x16x32_bf16(af0, bfr[jj][0], acc[mh * 4 + ii][nh * 2 + jj], 0, 0, 0);
                acc[mh * 4 + ii][nh * 2 + jj] =
                    __builtin_amdgcn_mfma_f32_16x16x32_bf16(af1, bfr[jj][1], acc[mh * 4 + ii][nh * 2 + jj], 0, 0, 0);
            }
        }
        __builtin_amdgcn_s_setprio(0);
    };
#define FENCE_BAR() do { asm volatile("" ::: "memory"); __builtin_amdgcn_s_barrier(); } while (0)

    // prologue: the 6 half-stages iter -1 would have issued (slot order p2..p7)
    stA(0, 0); stB(1, 0); stA(1, 0); stB(0, 0);
    stA(0, 1); stB(1, 1);

    for (int I = 0; I < NI; ++I) {
        const int te = 2 * I, to = te + 1;
        const bool lastI = (I == NI - 1);
        // p0: reads buf0 A-h0,B-h0 (te)
        asm volatile("s_waitcnt vmcnt(4)" ::: "memory");
        __builtin_amdgcn_s_barrier();
        stA(1, to);
        quad(te, 0, 0);
        FENCE_BAR();
        // p1: reads A-h0, B-h1
        stB(0, to);
        quad(te, 0, 1);
        FENCE_BAR();
        // p2: reads A-h1, B-h1   (A-h0(te) now dead -> stage A-h0(te+2))
        if (!lastI) stA(0, te + 2);
        quad(te, 1, 1);
        FENCE_BAR();
        // p3: reads A-h1, B-h0   (B-h1(te) dead)
        if (!lastI) stB(1, te + 2);
        quad(te, 1, 0);
        FENCE_BAR();
        // p4: reads buf1 A-h0,B-h0 (to)   (A-h1(te), B-h0(te) dead)
        if (lastI) { asm volatile("s_waitcnt vmcnt(0)" ::: "memory"); }
        else       { asm volatile("s_waitcnt vmcnt(4)" ::: "memory"); }
        __builtin_amdgcn_s_barrier();
        if (!lastI) stA(1, te + 2);
        quad(to, 0, 0);
        FENCE_BAR();
        // p5
        if (!lastI) stB(0, te + 2);
        quad(to, 0, 1);
        FENCE_BAR();
        // p6   (A-h0(to) dead)
        if (to + 2 < NT) stA(0, to + 2);
        quad(to, 1, 1);
        FENCE_BAR();
        // p7   (B-h1(to) dead)
        if (to + 2 < NT) stB(1, to + 2);
        quad(to, 1, 0);
        FENCE_BAR();
    }
#undef FENCE_BAR

#pragma unroll
    for (int mh = 0; mh < 2; ++mh)
#pragma unroll
    for (int ii = 0; ii < 4; ++ii) {
#pragma unroll
        for (int nh = 0; nh < 2; ++nh)
#pragma unroll
        for (int jj = 0; jj < 2; ++jj) {
            int c = col0 + nh * 128 + wc * 32 + jj * 16 + li;
            f32x4 a = acc[mh * 4 + ii][nh * 2 + jj];
            if constexpr (MODE == 0) {
                int part = c / 768, rem = c % 768;
                int h = rem >> 6, dd = rem & 63;
#pragma unroll
                for (int e = 0; e < 4; ++e) {
                    int r = row0 + mh * 128 + wr * 64 + ii * 16 + g * 4 + e;
                    int b = r >> 12, n = r & 4095;
                    ((u16*)out)[(((size_t)part * NHEADS + b * HH + h) * NN + n) * DD + dd] = f2b(a[e]);
                }
            } else {
                float bb = bias[c];
#pragma unroll
                for (int e = 0; e < 4; ++e) {
                    int r = row0 + mh * 128 + wr * 64 + ii * 16 + g * 4 + e;
                    ((float*)out)[(size_t)r * 768 + c] = a[e] + bb;
                }
            }
        }
    }
}

// ---------------------------------------------------------------- 128x128 bf16 GEMM (B^T form)  [round-5 verified: 146us]
template <int MODE>
__global__ __launch_bounds__(256) void gemm128d(const u16* __restrict__ A, const u16* __restrict__ Bm,
                                                const float* __restrict__ bias, void* __restrict__ out,
                                                int ncol) {
    constexpr int K = 768;
    __shared__ __align__(16) u16 lA[128 * 64];
    __shared__ __align__(16) u16 lB[128 * 64];
    const int tid = threadIdx.x;
    const int lane = tid & 63, wid = tid >> 6;
    const int wr = wid >> 1, wc = wid & 1;
    const int li = lane & 15, g = lane >> 4;

    const int nwg = gridDim.x, chunk = nwg >> 3;
    const int swz = ((int)blockIdx.x & 7) * chunk + ((int)blockIdx.x >> 3);
    const int col0 = (swz % ncol) * 128;
    const int row0 = (swz / ncol) * 128;

    const int lrow = lane >> 3;
    const int lcolsw = (((lane & 7) ^ lrow) * 8);

    f32x4 acc[4][4];
#pragma unroll
    for (int i = 0; i < 4; ++i)
#pragma unroll
        for (int j = 0; j < 4; ++j) acc[i][j] = zero4();

    for (int kt = 0; kt < K; kt += 64) {
#pragma unroll
        for (int s = 0; s < 4; ++s) {
            int r0 = wid * 32 + s * 8;
            gl_lds16(A  + (size_t)(row0 + r0 + lrow) * K + kt + lcolsw, lA + r0 * 64);
            gl_lds16(Bm + (size_t)(col0 + r0 + lrow) * K + kt + lcolsw, lB + r0 * 64);
        }
        __syncthreads();
#pragma unroll
        for (int kk = 0; kk < 64; kk += 32) {
            int kc = kk * 2 + (g << 4);
            bf16x8 af[4], bf_[4];
#pragma unroll
            for (int i = 0; i < 4; ++i) {
                int ra = wr * 64 + i * 16 + li;
                af[i] = *(const bf16x8*)((char*)lA + ((ra * 128 + kc) ^ ((ra & 7) << 4)));
                int rb = wc * 64 + i * 16 + li;
                bf_[i] = *(const bf16x8*)((char*)lB + ((rb * 128 + kc) ^ ((rb & 7) << 4)));
            }
#pragma unroll
            for (int i = 0; i < 4; ++i)
#pragma unroll
                for (int j = 0; j < 4; ++j)
                    acc[i][j] = __builtin_amdgcn_mfma_f32_16x16x32_bf16(af[i], bf_[j], acc[i][j], 0, 0, 0);
        }
        __syncthreads();
    }

#pragma unroll
    for (int i = 0; i < 4; ++i) {
#pragma unroll
        for (int j = 0; j < 4; ++j) {
            int c = col0 + wc * 64 + j * 16 + li;
            if constexpr (MODE == 0) {
                int part = c / 768, rem = c % 768;
                int h = rem >> 6, dd = rem & 63;
#pragma unroll
                for (int e = 0; e < 4; ++e) {
                    int r = row0 + wr * 64 + i * 16 + g * 4 + e;
                    int b = r >> 12, n = r & 4095;
                    ((u16*)out)[(((size_t)part * NHEADS + b * HH + h) * NN + n) * DD + dd] =
                        f2b(acc[i][j][e]);
                }
            } else {
                float bb = bias[c];
#pragma unroll
                for (int e = 0; e < 4; ++e) {
                    int r = row0 + wr * 64 + i * 16 + g * 4 + e;
                    ((float*)out)[(size_t)r * 768 + c] = acc[i][j][e] + bb;
                }
            }
        }
    }
}

// ---------------------------------------------------------------- K2: split-K kq partials via MFMA + v-mean
__global__ __launch_bounds__(256) void kq_mean(const u16* __restrict__ qkv, float* __restrict__ kqp,
                                               float* __restrict__ meanp) {
    const int head = blockIdx.x, part = blockIdx.y;
    const int tid = threadIdx.x, lane = tid & 63, wid = tid >> 6;
    __shared__ __align__(16) u16 tiles[4][2][32 * 64];
    __shared__ float sred[16 * 64];

    if (part == 4) {
        const u16* vh = qkv + 2 * QKVSZ + (size_t)head * NN * DD;
        int rg = tid >> 4, cg = tid & 15;
        float s0 = 0.f, s1 = 0.f, s2 = 0.f, s3 = 0.f;
        for (int it = 0; it < 256; ++it) {
            int n = rg + it * 16;
            u16x4 v = *(const u16x4*)(vh + (size_t)n * DD + cg * 4);
            s0 += b2f(v[0]); s1 += b2f(v[1]); s2 += b2f(v[2]); s3 += b2f(v[3]);
        }
        sred[rg * 64 + cg * 4 + 0] = s0;
        sred[rg * 64 + cg * 4 + 1] = s1;
        sred[rg * 64 + cg * 4 + 2] = s2;
        sred[rg * 64 + cg * 4 + 3] = s3;
        __syncthreads();
        if (tid < 64) {
            float s = 0.f;
#pragma unroll
            for (int rg2 = 0; rg2 < 16; ++rg2) s += sred[rg2 * 64 + tid];
            meanp[head * 64 + tid] = s;
        }
        return;
    }

    u16* kt = tiles[wid][0];
    u16* qt = tiles[wid][1];
    const u16* qh = qkv + (size_t)head * NN * DD;
    const u16* kh = qkv + QKVSZ + (size_t)head * NN * DD;
    const int nbase = part * 1024 + wid * 256;

    f32x4 acc[4][4];
#pragma unroll
    for (int i = 0; i < 4; ++i)
#pragma unroll
        for (int j = 0; j < 4; ++j) acc[i][j] = zero4();

    const int srow = lane >> 3, schunk = (lane & 7) * 8;
    const int g8 = (lane >> 4) * 8, li = lane & 15;

    for (int it = 0; it < 8; ++it) {
        int n0 = nbase + it * 32;
#pragma unroll
        for (int p = 0; p < 4; ++p) {
            int r = srow + p * 8;
            *(u16x8*)(kt + r * 64 + schunk) = *(const u16x8*)(kh + (size_t)(n0 + r) * DD + schunk);
            *(u16x8*)(qt + r * 64 + schunk) = *(const u16x8*)(qh + (size_t)(n0 + r) * DD + schunk);
        }
        bf16x8 af[4], bf_[4];
#pragma unroll
        for (int i = 0; i < 4; ++i)
#pragma unroll
            for (int j = 0; j < 8; ++j) af[i][j] = (short)kt[(g8 + j) * 64 + i * 16 + li];
#pragma unroll
        for (int i = 0; i < 4; ++i)
#pragma unroll
            for (int j = 0; j < 8; ++j) bf_[i][j] = (short)qt[(g8 + j) * 64 + i * 16 + li];
#pragma unroll
        for (int i = 0; i < 4; ++i)
#pragma unroll
            for (int j = 0; j < 4; ++j)
                acc[i][j] = __builtin_amdgcn_mfma_f32_16x16x32_bf16(af[i], bf_[j], acc[i][j], 0, 0, 0);
    }

    const int slot = part * 4 + wid;
    const int g = lane >> 4;
    float* dst = kqp + ((size_t)head * 16 + slot) * 4096;
#pragma unroll
    for (int i = 0; i < 4; ++i)
#pragma unroll
        for (int j = 0; j < 4; ++j)
#pragma unroll
            for (int e = 0; e < 4; ++e)
                dst[(i * 16 + g * 4 + e) * 64 + j * 16 + li] = acc[i][j][e];
}

// ---------------------------------------------------------------- K3: reduce partials, gate, fc+softmax
__global__ __launch_bounds__(256) void head_soft(
    const float* __restrict__ kqp, const float* __restrict__ meanp,
    const float* __restrict__ conv_w, const float* __restrict__ conv_b,
    const float* __restrict__ fc_w, const float* __restrict__ fc_b,
    const float* __restrict__ dw1_b, const float* __restrict__ dw2_b,
    float* __restrict__ sa_g, float* __restrict__ gate_g, float* __restrict__ effb) {
    const int head = blockIdx.x;
    const int tid = threadIdx.x;
    __shared__ float skq[64 * 64];
    __shared__ float sa[64 * 64];
    __shared__ float sgate[64];

    for (int idx = tid; idx < 4096; idx += 256) {
        float s = 0.f;
#pragma unroll
        for (int p = 0; p < 16; ++p) s += kqp[((size_t)head * 16 + p) * 4096 + idx];
        skq[idx] = s * 0.125f;
    }
    __syncthreads();
    if (tid < 64) {
        float gsum = conv_b[tid];
        for (int i = 0; i < 64; ++i)
            gsum += conv_w[(tid * 64 + i) * 5 + 2] * (meanp[head * 64 + i] * (1.f / 4096.f));
        float gt = 1.f / (1.f + __expf(-gsum));
        sgate[tid] = gt;
        gate_g[head * 64 + tid] = gt;
    }

    {
        int rr = tid >> 2, cg = (tid & 3) * 16;
        for (int c = cg; c < cg + 16; ++c) {
            float s = fc_b[c];
            for (int e = 0; e < 64; ++e) s += fmaxf(skq[rr * 64 + e], 0.f) * fc_w[c * 64 + e];
            sa[rr * 64 + c] = s + skq[rr * 64 + c];
        }
    }
    __syncthreads();
    if (tid < 64) {
        float m = -1e30f;
        for (int e = 0; e < 64; ++e) m = fmaxf(m, sa[tid * 64 + e]);
        float s = 0.f;
        for (int e = 0; e < 64; ++e) {
            float p = __expf(sa[tid * 64 + e] - m);
            sa[tid * 64 + e] = p;
            s += p;
        }
        float inv = 1.f / s;
        for (int e = 0; e < 64; ++e) sa[tid * 64 + e] *= inv;
    }
    __syncthreads();
    for (int idx = tid; idx < 4096; idx += 256) sa_g[(size_t)head * 4096 + idx] = sa[idx];
    if (tid < 64) {
        float s = 0.f;
        for (int e = 0; e < 64; ++e) s += sa[tid * 64 + e] * (dw1_b[e] + dw2_b[e]);
        effb[head * 64 + tid] = sgate[tid] * s;
    }
}

// ---------------------------------------------------------------- K4: fold a,gate,dw -> eff (bf16)
__global__ __launch_bounds__(256) void fold_eff(
    const float* __restrict__ sa_g, const float* __restrict__ gate_g,
    const float* __restrict__ dw1_w, const float* __restrict__ dw2_w,
    u16* __restrict__ eff) {
    const int head = blockIdx.x, ig = blockIdx.y;
    const int tid = threadIdx.x;
    __shared__ float ssa[4096];
    __shared__ float sw2[64 * 16 * 5];
    __shared__ float sw1[64 * 16 * 3];

    for (int idx = tid; idx < 4096; idx += 256) ssa[idx] = sa_g[(size_t)head * 4096 + idx];
    for (int idx = tid; idx < 64 * 16 * 5; idx += 256) {
        int e = idx / 80, rem = idx % 80, il = rem / 5, t = rem % 5;
        sw2[idx] = dw2_w[((size_t)(e * 64 + ig * 16 + il)) * 5 + t];
    }
    for (int idx = tid; idx < 64 * 16 * 3; idx += 256) {
        int e = idx / 48, rem = idx % 48, il = rem / 3, t = rem % 3;
        sw1[idx] = dw1_w[((size_t)(e * 64 + ig * 16 + il)) * 3 + t];
    }
    __syncthreads();

    const int il = tid & 15, og = tid >> 4;
    const int i = ig * 16 + il;
    float t[4][5];
#pragma unroll
    for (int o = 0; o < 4; ++o)
#pragma unroll
        for (int tp = 0; tp < 5; ++tp) t[o][tp] = 0.f;

    for (int e = 0; e < 64; ++e) {
        float a0 = ssa[(og * 4 + 0) * 64 + e];
        float a1 = ssa[(og * 4 + 1) * 64 + e];
        float a2 = ssa[(og * 4 + 2) * 64 + e];
        float a3 = ssa[(og * 4 + 3) * 64 + e];
        const float* w2 = sw2 + (e * 16 + il) * 5;
        const float* w1 = sw1 + (e * 16 + il) * 3;
        float c0 = w2[0], c1 = w2[1] + w1[0], c2 = w2[2] + w1[1], c3 = w2[3] + w1[2], c4 = w2[4];
        t[0][0] += a0 * c0; t[0][1] += a0 * c1; t[0][2] += a0 * c2; t[0][3] += a0 * c3; t[0][4] += a0 * c4;
        t[1][0] += a1 * c0; t[1][1] += a1 * c1; t[1][2] += a1 * c2; t[1][3] += a1 * c3; t[1][4] += a1 * c4;
        t[2][0] += a2 * c0; t[2][1] += a2 * c1; t[2][2] += a2 * c2; t[2][3] += a2 * c3; t[2][4] += a2 * c4;
        t[3][0] += a3 * c0; t[3][1] += a3 * c1; t[3][2] += a3 * c2; t[3][3] += a3 * c3; t[3][4] += a3 * c4;
    }
#pragma unroll
    for (int o = 0; o < 4; ++o) {
        int oo = og * 4 + o;
        float gt = gate_g[head * 64 + oo];
        u16* eo = eff + ((size_t)head * 64 + oo) * 320 + i;
#pragma unroll
        for (int tp = 0; tp < 5; ++tp) eo[tp * 64] = f2b(gt * t[o][tp]);
    }
}

// ---------------------------------------------------------------- fused conv+attend+gate -> attn (bf16)
__global__ __launch_bounds__(256) void conv_attn(const u16* __restrict__ qkv, const u16* __restrict__ eff,
                                                 const float* __restrict__ effb, u16* __restrict__ attn) {
    const int nt = blockIdx.x, head = blockIdx.y;
    const int tid = threadIdx.x, lane = tid & 63, wid = tid >> 6;
    __shared__ __align__(16) u16 vt[132 * 64];
    const int n0 = nt * 128;
    const u16* vh = qkv + 2 * QKVSZ + (size_t)head * NN * DD;

    {
        int sr = tid >> 3, sc = (tid & 7) * 8;
#pragma unroll
        for (int p = 0; p < 5; ++p) {
            int r = sr + p * 32;
            if (r < 132) {
                int n = n0 - 2 + r;
                u16x8 v = {0, 0, 0, 0, 0, 0, 0, 0};
                if (n >= 0 && n < NN) v = *(const u16x8*)(vh + (size_t)n * DD + sc);
                *(u16x8*)((char*)vt + ((r * 128 + sc * 2) ^ ((r & 7) << 4))) = v;
            }
        }
    }
    __syncthreads();

    f32x4 acc[2][4];
#pragma unroll
    for (int s = 0; s < 2; ++s)
#pragma unroll
        for (int j = 0; j < 4; ++j) acc[s][j] = zero4();

    const u16* effh = eff + (size_t)head * 64 * 320;
    const int li = lane & 15, g = lane >> 4;
#pragma unroll
    for (int s = 0; s < 10; ++s) {
        int tap = s >> 1, half = s & 1;
        bf16x8 bfr[4];
#pragma unroll
        for (int nj = 0; nj < 4; ++nj)
            bfr[nj] = *(const bf16x8*)(effh + (size_t)(nj * 16 + li) * 320 + s * 32 + g * 8);
        int kc = half * 64 + g * 16;
#pragma unroll
        for (int sub = 0; sub < 2; ++sub) {
            int rr = wid * 32 + sub * 16 + li + tap;
            bf16x8 afr = *(const bf16x8*)((char*)vt + ((rr * 128 + kc) ^ ((rr & 7) << 4)));
#pragma unroll
            for (int nj = 0; nj < 4; ++nj)
                acc[sub][nj] = __builtin_amdgcn_mfma_f32_16x16x32_bf16(afr, bfr[nj], acc[sub][nj], 0, 0, 0);
        }
    }

    const int b = head / HH, h = head % HH;
#pragma unroll
    for (int sub = 0; sub < 2; ++sub)
#pragma unroll
        for (int nj = 0; nj < 4; ++nj) {
            int o = nj * 16 + li;
            float bb = effb[head * 64 + o];
#pragma unroll
            for (int e = 0; e < 4; ++e) {
                int m = wid * 32 + sub * 16 + g * 4 + e;
                size_t n = (size_t)n0 + m;
                attn[((size_t)b * NN + n) * CC + h * DD + o] = f2b(acc[sub][nj][e] + bb);
            }
        }
}

// ---------------------------------------------------------------- launch
extern "C" void kernel_launch(void* const* d_in, const int* in_sizes, int n_in,
                              void* d_out, int out_size, void* d_ws, size_t ws_size,
                              hipStream_t stream) {
    const float* x      = (const float*)d_in[0];
    const float* qkv_w  = (const float*)d_in[1];
    const float* proj_w = (const float*)d_in[2];
    const float* proj_b = (const float*)d_in[3];
    const float* conv_w = (const float*)d_in[4];
    const float* conv_b = (const float*)d_in[5];
    const float* fc_w   = (const float*)d_in[6];
    const float* fc_b   = (const float*)d_in[7];
    const float* dw1_w  = (const float*)d_in[8];
    const float* dw1_b  = (const float*)d_in[9];
    const float* dw2_w  = (const float*)d_in[10];
    const float* dw2_b  = (const float*)d_in[11];

    char* ws = (char*)d_ws;
    u16* xb    = (u16*)(ws);                       // 50,331,648 B (dead after gemm<0>)
    u16* wqkv  = (u16*)(ws + 50331648);            //  3,538,944 B
    u16* wproj = (u16*)(ws + 53870592);            //  1,179,648 B
    u16* qkv   = (u16*)(ws + 55050240);            // 150,994,944 B
    u16* eff   = (u16*)(ws + 206045184);           //  3,932,160 B
    float* effb = (float*)(ws + 209977344);        //     24,576 B
    u16* attn  = (u16*)(ws + 210001920);           // 50,331,648 B

    // overlay into xb region (only used after gemm<0> has consumed xb)
    float* kqp    = (float*)(ws);                  // 25,165,824 B
    float* meanp  = (float*)(ws + 25165824);       //     24,576 B
    float* sa_g   = (float*)(ws + 25190400);       //  1,572,864 B
    float* gate_g = (float*)(ws + 26763264);       //     24,576 B

    float* out = (float*)d_out;

    cast_all<<<2048, 256, 0, stream>>>(x, qkv_w, proj_w, xb, wqkv, wproj);

    // QKV: 256x256 tiles: 128 x 9 = 1152 blocks (%8==0), fixed 8-phase schedule.
    gemm256p<0><<<1152, 512, 0, stream>>>(xb, wqkv, nullptr, qkv, 9);

    kq_mean<<<dim3(96, 5), 256, 0, stream>>>(qkv, kqp, meanp);
    head_soft<<<96, 256, 0, stream>>>(kqp, meanp, conv_w, conv_b, fc_w, fc_b,
                                      dw1_b, dw2_b, sa_g, gate_g, effb);
    fold_eff<<<dim3(96, 4), 256, 0, stream>>>(sa_g, gate_g, dw1_w, dw2_w, eff);

    conv_attn<<<dim3(32, 96), 256, 0, stream>>>(qkv, eff, effb, attn);

    // proj: 1536 blocks (%8==0), 6 col tiles (proven gemm128d).
    gemm128d<1><<<1536, 256, 0, stream>>>(attn, wproj, proj_b, out, 6);
}

// Round 11
// 386.971 us; speedup vs baseline: 1.1058x; 1.1058x over previous
//
#include <hip/hip_runtime.h>
#include <hip/hip_bf16.h>
#include <cstdint>
#include <cstddef>

typedef unsigned short u16;
typedef __attribute__((ext_vector_type(4))) unsigned short u16x4;
typedef __attribute__((ext_vector_type(8))) unsigned short u16x8;
typedef __attribute__((ext_vector_type(8))) short bf16x8;
typedef __attribute__((ext_vector_type(4))) float f32x4;

#define BB 8
#define NN 4096
#define CC 768
#define HH 12
#define DD 64
#define NHEADS 96           // B*H
#define QKVSZ 25165824LL    // 96*4096*64 elements per q/k/v plane

__device__ inline float b2f(u16 u) { return __uint_as_float(((unsigned)u) << 16); }
__device__ inline u16 f2b(float f) {
    unsigned u = __float_as_uint(f);
    return (u16)((u + 0x7fffu + ((u >> 16) & 1u)) >> 16);
}
__device__ inline f32x4 zero4() { f32x4 z = {0.f, 0.f, 0.f, 0.f}; return z; }

// direct global->LDS DMA, 16B per lane. LDS dest is wave-uniform base
// (HW adds lane*16); global src is per-lane (pre-swizzled for conflict-free reads).
__device__ __forceinline__ void gl_lds16(const u16* g, u16* l) {
    __builtin_amdgcn_global_load_lds(
        (const __attribute__((address_space(1))) void*)g,
        (__attribute__((address_space(3))) void*)l, 16, 0, 0);
}

// ---------------------------------------------------------------- fused casts f32->bf16 (x, qkv_w, proj_w)
__global__ void cast_all(const float* __restrict__ x, const float* __restrict__ w1,
                         const float* __restrict__ w2, u16* __restrict__ xb,
                         u16* __restrict__ wqkv, u16* __restrict__ wproj) {
    const long n0 = 25165824, n1 = 1769472, n2 = 589824;
    long i0 = (long)(blockIdx.x * blockDim.x + threadIdx.x) * 4;
    long stride = (long)gridDim.x * blockDim.x * 4;
    for (long j = i0; j < n0 + n1 + n2; j += stride) {
        const float* s; u16* d; long k;
        if (j < n0)            { s = x;  d = xb;    k = j; }
        else if (j < n0 + n1)  { s = w1; d = wqkv;  k = j - n0; }
        else                   { s = w2; d = wproj; k = j - n0 - n1; }
        float4 v = *(const float4*)(s + k);
        u16x4 o;
        o[0] = f2b(v.x); o[1] = f2b(v.y); o[2] = f2b(v.z); o[3] = f2b(v.w);
        *(u16x4*)(d + k) = o;
    }
}

// ---------------------------------------------------------------- 128x128 bf16 GEMM (B^T form)  [round-5/8 verified: 144us]
// Staging: global_load_lds (linear LDS dest) with INVERSE-swizzled global source
// column (unit ^= row&7); fragment reads use the same involution -> 0 conflicts.
// Grid: 1D, bijective XCD chunking (nwg%8==0), col-tile fastest within chunk.
// MODE 0: scatter-store qkv bf16 [3][B][H][N][64].  MODE 1: +bias, fp32 [M][768].
template <int MODE>
__global__ __launch_bounds__(256) void gemm128d(const u16* __restrict__ A, const u16* __restrict__ Bm,
                                                const float* __restrict__ bias, void* __restrict__ out,
                                                int ncol) {
    constexpr int K = 768;
    __shared__ __align__(16) u16 lA[128 * 64];
    __shared__ __align__(16) u16 lB[128 * 64];
    const int tid = threadIdx.x;
    const int lane = tid & 63, wid = tid >> 6;
    const int wr = wid >> 1, wc = wid & 1;
    const int li = lane & 15, g = lane >> 4;

    const int nwg = gridDim.x, chunk = nwg >> 3;
    const int swz = ((int)blockIdx.x & 7) * chunk + ((int)blockIdx.x >> 3);
    const int col0 = (swz % ncol) * 128;
    const int row0 = (swz / ncol) * 128;

    const int lrow = lane >> 3;
    const int lcolsw = (((lane & 7) ^ lrow) * 8);

    f32x4 acc[4][4];
#pragma unroll
    for (int i = 0; i < 4; ++i)
#pragma unroll
        for (int j = 0; j < 4; ++j) acc[i][j] = zero4();

    for (int kt = 0; kt < K; kt += 64) {
#pragma unroll
        for (int s = 0; s < 4; ++s) {
            int r0 = wid * 32 + s * 8;
            gl_lds16(A  + (size_t)(row0 + r0 + lrow) * K + kt + lcolsw, lA + r0 * 64);
            gl_lds16(Bm + (size_t)(col0 + r0 + lrow) * K + kt + lcolsw, lB + r0 * 64);
        }
        __syncthreads();
#pragma unroll
        for (int kk = 0; kk < 64; kk += 32) {
            int kc = kk * 2 + (g << 4);
            bf16x8 af[4], bf_[4];
#pragma unroll
            for (int i = 0; i < 4; ++i) {
                int ra = wr * 64 + i * 16 + li;
                af[i] = *(const bf16x8*)((char*)lA + ((ra * 128 + kc) ^ ((ra & 7) << 4)));
                int rb = wc * 64 + i * 16 + li;
                bf_[i] = *(const bf16x8*)((char*)lB + ((rb * 128 + kc) ^ ((rb & 7) << 4)));
            }
#pragma unroll
            for (int i = 0; i < 4; ++i)
#pragma unroll
                for (int j = 0; j < 4; ++j)
                    acc[i][j] = __builtin_amdgcn_mfma_f32_16x16x32_bf16(af[i], bf_[j], acc[i][j], 0, 0, 0);
        }
        __syncthreads();
    }

#pragma unroll
    for (int i = 0; i < 4; ++i) {
#pragma unroll
        for (int j = 0; j < 4; ++j) {
            int c = col0 + wc * 64 + j * 16 + li;
            if constexpr (MODE == 0) {
                int part = c / 768, rem = c % 768;
                int h = rem >> 6, dd = rem & 63;
#pragma unroll
                for (int e = 0; e < 4; ++e) {
                    int r = row0 + wr * 64 + i * 16 + g * 4 + e;
                    int b = r >> 12, n = r & 4095;
                    ((u16*)out)[(((size_t)part * NHEADS + b * HH + h) * NN + n) * DD + dd] =
                        f2b(acc[i][j][e]);
                }
            } else {
                float bb = bias[c];
#pragma unroll
                for (int e = 0; e < 4; ++e) {
                    int r = row0 + wr * 64 + i * 16 + g * 4 + e;
                    ((float*)out)[(size_t)r * 768 + c] = acc[i][j][e] + bb;
                }
            }
        }
    }
}

// ---------------------------------------------------------------- K2: split-K kq partials via MFMA + v-mean chunks
// grid (96, 8). y<4: kq partial (wave-private 256-token chunks, no barriers).
//               y in 4..7: v-mean over 1024 tokens -> meanp[head][y-4][64] (raw sums).
__global__ __launch_bounds__(256) void kq_mean(const u16* __restrict__ qkv, float* __restrict__ kqp,
                                               float* __restrict__ meanp) {
    const int head = blockIdx.x, part = blockIdx.y;
    const int tid = threadIdx.x, lane = tid & 63, wid = tid >> 6;
    __shared__ __align__(16) u16 tiles[4][2][32 * 64];
    __shared__ float sred[16 * 64];

    if (part >= 4) {
        const int chunkid = part - 4;
        const u16* vh = qkv + 2 * QKVSZ + (size_t)head * NN * DD + (size_t)chunkid * 1024 * DD;
        int rg = tid >> 4, cg = tid & 15;
        float s0 = 0.f, s1 = 0.f, s2 = 0.f, s3 = 0.f;
        for (int it = 0; it < 64; ++it) {
            int n = rg + it * 16;
            u16x4 v = *(const u16x4*)(vh + (size_t)n * DD + cg * 4);
            s0 += b2f(v[0]); s1 += b2f(v[1]); s2 += b2f(v[2]); s3 += b2f(v[3]);
        }
        sred[rg * 64 + cg * 4 + 0] = s0;
        sred[rg * 64 + cg * 4 + 1] = s1;
        sred[rg * 64 + cg * 4 + 2] = s2;
        sred[rg * 64 + cg * 4 + 3] = s3;
        __syncthreads();
        if (tid < 64) {
            float s = 0.f;
#pragma unroll
            for (int rg2 = 0; rg2 < 16; ++rg2) s += sred[rg2 * 64 + tid];
            meanp[(head * 4 + chunkid) * 64 + tid] = s;
        }
        return;
    }

    u16* kt = tiles[wid][0];
    u16* qt = tiles[wid][1];
    const u16* qh = qkv + (size_t)head * NN * DD;
    const u16* kh = qkv + QKVSZ + (size_t)head * NN * DD;
    const int nbase = part * 1024 + wid * 256;

    f32x4 acc[4][4];
#pragma unroll
    for (int i = 0; i < 4; ++i)
#pragma unroll
        for (int j = 0; j < 4; ++j) acc[i][j] = zero4();

    const int srow = lane >> 3, schunk = (lane & 7) * 8;
    const int g8 = (lane >> 4) * 8, li = lane & 15;

    for (int it = 0; it < 8; ++it) {
        int n0 = nbase + it * 32;
#pragma unroll
        for (int p = 0; p < 4; ++p) {
            int r = srow + p * 8;
            *(u16x8*)(kt + r * 64 + schunk) = *(const u16x8*)(kh + (size_t)(n0 + r) * DD + schunk);
            *(u16x8*)(qt + r * 64 + schunk) = *(const u16x8*)(qh + (size_t)(n0 + r) * DD + schunk);
        }
        bf16x8 af[4], bf_[4];
#pragma unroll
        for (int i = 0; i < 4; ++i)
#pragma unroll
            for (int j = 0; j < 8; ++j) af[i][j] = (short)kt[(g8 + j) * 64 + i * 16 + li];
#pragma unroll
        for (int i = 0; i < 4; ++i)
#pragma unroll
            for (int j = 0; j < 8; ++j) bf_[i][j] = (short)qt[(g8 + j) * 64 + i * 16 + li];
#pragma unroll
        for (int i = 0; i < 4; ++i)
#pragma unroll
            for (int j = 0; j < 4; ++j)
                acc[i][j] = __builtin_amdgcn_mfma_f32_16x16x32_bf16(af[i], bf_[j], acc[i][j], 0, 0, 0);
    }

    const int slot = part * 4 + wid;
    const int g = lane >> 4;
    float* dst = kqp + ((size_t)head * 16 + slot) * 4096;
#pragma unroll
    for (int i = 0; i < 4; ++i)
#pragma unroll
        for (int j = 0; j < 4; ++j)
#pragma unroll
            for (int e = 0; e < 4; ++e)
                dst[(i * 16 + g * 4 + e) * 64 + j * 16 + li] = acc[i][j][e];
}

// ---------------------------------------------------------------- K3: reduce partials, gate, fc+softmax (512 thr)
// 96 blocks. Writes sa_g[head][o][e] (softmax probs), gate_g[head][o], effb[head][o].
__global__ __launch_bounds__(512) void head_soft(
    const float* __restrict__ kqp, const float* __restrict__ meanp,
    const float* __restrict__ conv_w, const float* __restrict__ conv_b,
    const float* __restrict__ fc_w, const float* __restrict__ fc_b,
    const float* __restrict__ dw1_b, const float* __restrict__ dw2_b,
    float* __restrict__ sa_g, float* __restrict__ gate_g, float* __restrict__ effb) {
    const int head = blockIdx.x;
    const int tid = threadIdx.x;
    __shared__ float skq[64 * 64];
    __shared__ float sa[64 * 64];
    __shared__ float sgate[64];

    // reduce kq partials (x0.125 scale)
    for (int idx = tid; idx < 4096; idx += 512) {
        float s = 0.f;
#pragma unroll
        for (int p = 0; p < 16; ++p) s += kqp[((size_t)head * 16 + p) * 4096 + idx];
        skq[idx] = s * 0.125f;
    }
    __syncthreads();
    if (tid < 64) {
        float gsum = conv_b[tid];
        for (int i = 0; i < 64; ++i) {
            float mi = (meanp[(head * 4 + 0) * 64 + i] + meanp[(head * 4 + 1) * 64 + i] +
                        meanp[(head * 4 + 2) * 64 + i] + meanp[(head * 4 + 3) * 64 + i]) * (1.f / 4096.f);
            gsum += conv_w[(tid * 64 + i) * 5 + 2] * mi;
        }
        float gt = 1.f / (1.f + __expf(-gsum));
        sgate[tid] = gt;
        gate_g[head * 64 + tid] = gt;
    }

    // a = relu(kq)@fc^T + fc_b; logits = a + kq   (512 thr: 8 cols each)
    {
        int rr = tid >> 3, cg = (tid & 7) * 8;
        for (int c = cg; c < cg + 8; ++c) {
            float s = fc_b[c];
            for (int e = 0; e < 64; ++e) s += fmaxf(skq[rr * 64 + e], 0.f) * fc_w[c * 64 + e];
            sa[rr * 64 + c] = s + skq[rr * 64 + c];
        }
    }
    __syncthreads();
    if (tid < 64) {
        float m = -1e30f;
        for (int e = 0; e < 64; ++e) m = fmaxf(m, sa[tid * 64 + e]);
        float s = 0.f;
        for (int e = 0; e < 64; ++e) {
            float p = __expf(sa[tid * 64 + e] - m);
            sa[tid * 64 + e] = p;
            s += p;
        }
        float inv = 1.f / s;
        for (int e = 0; e < 64; ++e) sa[tid * 64 + e] *= inv;
    }
    __syncthreads();
    for (int idx = tid; idx < 4096; idx += 512) sa_g[(size_t)head * 4096 + idx] = sa[idx];
    if (tid < 64) {
        float s = 0.f;
        for (int e = 0; e < 64; ++e) s += sa[tid * 64 + e] * (dw1_b[e] + dw2_b[e]);
        effb[head * 64 + tid] = sgate[tid] * s;
    }
}

// ---------------------------------------------------------------- K4: fold a,gate,dw -> eff (bf16)
// grid (96,4): block handles 16 i's. thread: il=tid&15 (i), og=tid>>4 (4 o's each).
__global__ __launch_bounds__(256) void fold_eff(
    const float* __restrict__ sa_g, const float* __restrict__ gate_g,
    const float* __restrict__ dw1_w, const float* __restrict__ dw2_w,
    u16* __restrict__ eff) {
    const int head = blockIdx.x, ig = blockIdx.y;
    const int tid = threadIdx.x;
    __shared__ float ssa[4096];
    __shared__ float sw2[64 * 16 * 5];
    __shared__ float sw1[64 * 16 * 3];

    for (int idx = tid; idx < 4096; idx += 256) ssa[idx] = sa_g[(size_t)head * 4096 + idx];
    for (int idx = tid; idx < 64 * 16 * 5; idx += 256) {
        int e = idx / 80, rem = idx % 80, il = rem / 5, t = rem % 5;
        sw2[idx] = dw2_w[((size_t)(e * 64 + ig * 16 + il)) * 5 + t];
    }
    for (int idx = tid; idx < 64 * 16 * 3; idx += 256) {
        int e = idx / 48, rem = idx % 48, il = rem / 3, t = rem % 3;
        sw1[idx] = dw1_w[((size_t)(e * 64 + ig * 16 + il)) * 3 + t];
    }
    __syncthreads();

    const int il = tid & 15, og = tid >> 4;
    const int i = ig * 16 + il;
    float t[4][5];
#pragma unroll
    for (int o = 0; o < 4; ++o)
#pragma unroll
        for (int tp = 0; tp < 5; ++tp) t[o][tp] = 0.f;

    for (int e = 0; e < 64; ++e) {
        float a0 = ssa[(og * 4 + 0) * 64 + e];
        float a1 = ssa[(og * 4 + 1) * 64 + e];
        float a2 = ssa[(og * 4 + 2) * 64 + e];
        float a3 = ssa[(og * 4 + 3) * 64 + e];
        const float* w2 = sw2 + (e * 16 + il) * 5;
        const float* w1 = sw1 + (e * 16 + il) * 3;
        float c0 = w2[0], c1 = w2[1] + w1[0], c2 = w2[2] + w1[1], c3 = w2[3] + w1[2], c4 = w2[4];
        t[0][0] += a0 * c0; t[0][1] += a0 * c1; t[0][2] += a0 * c2; t[0][3] += a0 * c3; t[0][4] += a0 * c4;
        t[1][0] += a1 * c0; t[1][1] += a1 * c1; t[1][2] += a1 * c2; t[1][3] += a1 * c3; t[1][4] += a1 * c4;
        t[2][0] += a2 * c0; t[2][1] += a2 * c1; t[2][2] += a2 * c2; t[2][3] += a2 * c3; t[2][4] += a2 * c4;
        t[3][0] += a3 * c0; t[3][1] += a3 * c1; t[3][2] += a3 * c2; t[3][3] += a3 * c3; t[3][4] += a3 * c4;
    }
#pragma unroll
    for (int o = 0; o < 4; ++o) {
        int oo = og * 4 + o;
        float gt = gate_g[head * 64 + oo];
        u16* eo = eff + ((size_t)head * 64 + oo) * 320 + i;
#pragma unroll
        for (int tp = 0; tp < 5; ++tp) eo[tp * 64] = f2b(gt * t[o][tp]);
    }
}

// ---------------------------------------------------------------- fused conv+attend+gate -> attn (bf16)
__global__ __launch_bounds__(256) void conv_attn(const u16* __restrict__ qkv, const u16* __restrict__ eff,
                                                 const float* __restrict__ effb, u16* __restrict__ attn) {
    const int nt = blockIdx.x, head = blockIdx.y;
    const int tid = threadIdx.x, lane = tid & 63, wid = tid >> 6;
    __shared__ __align__(16) u16 vt[132 * 64];
    const int n0 = nt * 128;
    const u16* vh = qkv + 2 * QKVSZ + (size_t)head * NN * DD;

    {
        int sr = tid >> 3, sc = (tid & 7) * 8;
#pragma unroll
        for (int p = 0; p < 5; ++p) {
            int r = sr + p * 32;
            if (r < 132) {
                int n = n0 - 2 + r;
                u16x8 v = {0, 0, 0, 0, 0, 0, 0, 0};
                if (n >= 0 && n < NN) v = *(const u16x8*)(vh + (size_t)n * DD + sc);
                *(u16x8*)((char*)vt + ((r * 128 + sc * 2) ^ ((r & 7) << 4))) = v;
            }
        }
    }
    __syncthreads();

    f32x4 acc[2][4];
#pragma unroll
    for (int s = 0; s < 2; ++s)
#pragma unroll
        for (int j = 0; j < 4; ++j) acc[s][j] = zero4();

    const u16* effh = eff + (size_t)head * 64 * 320;
    const int li = lane & 15, g = lane >> 4;
#pragma unroll
    for (int s = 0; s < 10; ++s) {
        int tap = s >> 1, half = s & 1;
        bf16x8 bfr[4];
#pragma unroll
        for (int nj = 0; nj < 4; ++nj)
            bfr[nj] = *(const bf16x8*)(effh + (size_t)(nj * 16 + li) * 320 + s * 32 + g * 8);
        int kc = half * 64 + g * 16;
#pragma unroll
        for (int sub = 0; sub < 2; ++sub) {
            int rr = wid * 32 + sub * 16 + li + tap;
            bf16x8 afr = *(const bf16x8*)((char*)vt + ((rr * 128 + kc) ^ ((rr & 7) << 4)));
#pragma unroll
            for (int nj = 0; nj < 4; ++nj)
                acc[sub][nj] = __builtin_amdgcn_mfma_f32_16x16x32_bf16(afr, bfr[nj], acc[sub][nj], 0, 0, 0);
        }
    }

    const int b = head / HH, h = head % HH;
#pragma unroll
    for (int sub = 0; sub < 2; ++sub)
#pragma unroll
        for (int nj = 0; nj < 4; ++nj) {
            int o = nj * 16 + li;
            float bb = effb[head * 64 + o];
#pragma unroll
            for (int e = 0; e < 4; ++e) {
                int m = wid * 32 + sub * 16 + g * 4 + e;
                size_t n = (size_t)n0 + m;
                attn[((size_t)b * NN + n) * CC + h * DD + o] = f2b(acc[sub][nj][e] + bb);
            }
        }
}

// ---------------------------------------------------------------- launch
extern "C" void kernel_launch(void* const* d_in, const int* in_sizes, int n_in,
                              void* d_out, int out_size, void* d_ws, size_t ws_size,
                              hipStream_t stream) {
    const float* x      = (const float*)d_in[0];
    const float* qkv_w  = (const float*)d_in[1];
    const float* proj_w = (const float*)d_in[2];
    const float* proj_b = (const float*)d_in[3];
    const float* conv_w = (const float*)d_in[4];
    const float* conv_b = (const float*)d_in[5];
    const float* fc_w   = (const float*)d_in[6];
    const float* fc_b   = (const float*)d_in[7];
    const float* dw1_w  = (const float*)d_in[8];
    const float* dw1_b  = (const float*)d_in[9];
    const float* dw2_w  = (const float*)d_in[10];
    const float* dw2_b  = (const float*)d_in[11];

    char* ws = (char*)d_ws;
    u16* xb    = (u16*)(ws);                       // 50,331,648 B (dead after gemm<0>)
    u16* wqkv  = (u16*)(ws + 50331648);            //  3,538,944 B
    u16* wproj = (u16*)(ws + 53870592);            //  1,179,648 B
    u16* qkv   = (u16*)(ws + 55050240);            // 150,994,944 B
    u16* eff   = (u16*)(ws + 206045184);           //  3,932,160 B
    float* effb = (float*)(ws + 209977344);        //     24,576 B
    u16* attn  = (u16*)(ws + 210001920);           // 50,331,648 B

    // overlay into xb region (only used after gemm<0> has consumed xb)
    float* kqp    = (float*)(ws);                  // 25,165,824 B
    float* meanp  = (float*)(ws + 25165824);       //     98,304 B (96*4*64 f32)
    float* sa_g   = (float*)(ws + 25264128);       //  1,572,864 B
    float* gate_g = (float*)(ws + 26836992);       //     24,576 B

    float* out = (float*)d_out;

    cast_all<<<2048, 256, 0, stream>>>(x, qkv_w, proj_w, xb, wqkv, wproj);

    // QKV: 4608 blocks (%8==0), 18 col tiles.
    gemm128d<0><<<4608, 256, 0, stream>>>(xb, wqkv, nullptr, qkv, 18);

    kq_mean<<<dim3(96, 8), 256, 0, stream>>>(qkv, kqp, meanp);
    head_soft<<<96, 512, 0, stream>>>(kqp, meanp, conv_w, conv_b, fc_w, fc_b,
                                      dw1_b, dw2_b, sa_g, gate_g, effb);
    fold_eff<<<dim3(96, 4), 256, 0, stream>>>(sa_g, gate_g, dw1_w, dw2_w, eff);

    conv_attn<<<dim3(32, 96), 256, 0, stream>>>(qkv, eff, effb, attn);

    // proj: 1536 blocks (%8==0), 6 col tiles.
    gemm128d<1><<<1536, 256, 0, stream>>>(attn, wproj, proj_b, out, 6);
}